// Round 1
// baseline (1612.789 us; speedup 1.0000x reference)
//
#include <hip/hip_runtime.h>
#include <hip/hip_bf16.h>

// B=256, L=2048, H=128, V=32000, THR=0.4, LN_EPS=1e-5. All fp32.
// Htab2 row (RS=136 floats, padded for LDS bank-disjointness):
//   [0:64)=h[0..63], [64:68)=pad, [68:132)=h[64..127], [132]=kk, [133]=inv.
// Scan v2: rank-1 lookahead. vp_t = (M_{t-2} k_t) + g_{t-1} e_{t-1} (k_{t-1}.k_t),
// so the full matvec runs one step early (post-barrier, hides red read) and the
// gate->vp path is a single FMA. c_t = k_t.k_{t+1} piggybacks the ||e||^2 DPP
// tree through the same single barrier. Pending M update applied next step
// (k_{t-1} still in regs), skipped by uniform scalar branch when gate==0.

#define BB 256
#define LL 2048
#define HH 128
#define VV 32000
#define RS 136

typedef float f32x2 __attribute__((ext_vector_type(2)));

__device__ __forceinline__ void dma16(const float* g, float* l) {
  __builtin_amdgcn_global_load_lds(
      (const __attribute__((address_space(1))) void*)g,
      (__attribute__((address_space(3))) void*)l,
      16, 0, 0);
}

template <int CTRL>
__device__ __forceinline__ float dppadd(float x) {
  int y = __builtin_amdgcn_update_dpp(0, __float_as_int(x), CTRL, 0xF, 0xF, true);
  return x + __int_as_float(y);
}

// d = a*b + d  (packed 2x fp32)
__device__ __forceinline__ void pkfma(f32x2& d, f32x2 a, f32x2 b) {
  asm("v_pk_fma_f32 %0, %1, %2, %0" : "+v"(d) : "v"(a), "v"(b));
}

__device__ __forceinline__ void barrier_lgkm() {
  asm volatile("s_waitcnt lgkmcnt(0)\n\ts_barrier" ::: "memory");
}
__device__ __forceinline__ void wait_vm1() {
  asm volatile("s_waitcnt vmcnt(1)" ::: "memory");
}
__device__ __forceinline__ void wait_vm0() {
  asm volatile("s_waitcnt vmcnt(0)" ::: "memory");
}

// ---------------------------------------------------------------------------
// Kernel A: Htab2 row = LN(e + relu(e@W1+b1)@W2 + b2) (+ kk, inv), padded.
// (unchanged from verified baseline)
// ---------------------------------------------------------------------------
__global__ __launch_bounds__(256, 1) void build_htab_kernel(
    const float* __restrict__ embed,
    const float* __restrict__ W1,
    const float* __restrict__ b1,
    const float* __restrict__ W2,
    const float* __restrict__ b2,
    const float* __restrict__ gamma,
    const float* __restrict__ beta,
    float* __restrict__ Htab2)
{
  const int tid = threadIdx.x;
  const int j   = tid & 127;
  const int h2  = tid >> 7;

  float w1r[128];
#pragma unroll
  for (int m = 0; m < 128; ++m) w1r[m] = W1[m * 256 + tid];

  const float b1n = b1[tid];
  const float b2j = b2[j];
  const float gj  = gamma[j];
  const float bj  = beta[j];

  __shared__ __align__(16) float4 w2q[64][128];   // 128 KiB
  __shared__ __align__(16) float e_s[128];
  __shared__ __align__(16) float a_s[256];
  __shared__ float p_s[2][128];
  __shared__ float red[8];

  for (int idx = tid; idx < 8192; idx += 256) {
    int n4 = idx >> 7, jj = idx & 127;
    float4 w;
    w.x = W2[(size_t)(4 * n4 + 0) * 128 + jj];
    w.y = W2[(size_t)(4 * n4 + 1) * 128 + jj];
    w.z = W2[(size_t)(4 * n4 + 2) * 128 + jj];
    w.w = W2[(size_t)(4 * n4 + 3) * 128 + jj];
    w2q[n4][jj] = w;
  }
  __syncthreads();

  for (int v = blockIdx.x; v < VV; v += gridDim.x) {
    if (tid < 128) e_s[tid] = embed[(size_t)v * 128 + tid];
    __syncthreads();

    float acc[4] = {b1n, 0.f, 0.f, 0.f};
#pragma unroll
    for (int q = 0; q < 32; ++q) {
      float4 ev = *(const float4*)&e_s[4 * q];
      float t = ev.x * w1r[4 * q + 0];
      t = fmaf(ev.y, w1r[4 * q + 1], t);
      t = fmaf(ev.z, w1r[4 * q + 2], t);
      t = fmaf(ev.w, w1r[4 * q + 3], t);
      acc[q & 3] += t;
    }
    float a = fmaxf((acc[0] + acc[1]) + (acc[2] + acc[3]), 0.0f);
    a_s[tid] = a;
    __syncthreads();

    float p0 = 0.f, p1 = 0.f, p2v = 0.f, p3 = 0.f;
#pragma unroll
    for (int q = 0; q < 32; ++q) {
      int n4 = h2 * 32 + q;
      float4 av = *(const float4*)&a_s[4 * n4];
      float4 wq = w2q[n4][j];
      p0 = fmaf(av.x, wq.x, p0);
      p1 = fmaf(av.y, wq.y, p1);
      p2v = fmaf(av.z, wq.z, p2v);
      p3 = fmaf(av.w, wq.w, p3);
    }
    p_s[h2][j] = (p0 + p1) + (p2v + p3);
    __syncthreads();

    float y = 0.0f;
    if (tid < 128) {
      float ff = p_s[0][tid] + p_s[1][tid] + b2j;
      y = e_s[tid] + ff;
    }
    float s1 = y, s2 = y * y;
    s1 = dppadd<0xB1>(s1);  s2 = dppadd<0xB1>(s2);
    s1 = dppadd<0x4E>(s1);  s2 = dppadd<0x4E>(s2);
    s1 = dppadd<0x141>(s1); s2 = dppadd<0x141>(s2);
    s1 = dppadd<0x140>(s1); s2 = dppadd<0x140>(s2);
    s1 = dppadd<0x142>(s1); s2 = dppadd<0x142>(s2);
    s1 = dppadd<0x143>(s1); s2 = dppadd<0x143>(s2);
    if (tid < 128 && (tid & 63) == 63) {
      red[tid >> 6] = s1;
      red[2 + (tid >> 6)] = s2;
    }
    __syncthreads();
    float mu = (red[0] + red[1]) * (1.0f / 128.0f);
    float ms = (red[2] + red[3]) * (1.0f / 128.0f);
    float var = ms - mu * mu;
    float hv = 0.0f;
    if (tid < 128) {
      float dy = y - mu;
      hv = dy * (1.0f / sqrtf(var + 1e-5f)) * gj + bj;
      int ofs = tid + ((tid >> 6) << 2);           // padded layout
      Htab2[(size_t)v * RS + ofs] = hv;
    }
    float q2 = hv * hv;
    q2 = dppadd<0xB1>(q2);
    q2 = dppadd<0x4E>(q2);
    q2 = dppadd<0x141>(q2);
    q2 = dppadd<0x140>(q2);
    q2 = dppadd<0x142>(q2);
    q2 = dppadd<0x143>(q2);
    if (tid < 128 && (tid & 63) == 63) red[4 + (tid >> 6)] = q2;
    __syncthreads();
    if (tid == 0) {
      float kk = red[4] + red[5];
      Htab2[(size_t)v * RS + 132] = kk;
      Htab2[(size_t)v * RS + 133] = 1.0f / (kk + 1e-6f);
    }
    __syncthreads();
  }
}

// ---------------------------------------------------------------------------
// Kernel B: per-batch scan with rank-1 lookahead. 256 blocks x 256 threads.
// Thread (i=tid>>1, half=tid&1) owns M[i][64*half..+63] as 32 f32x2.
// Invariants entering step(t):
//   kc = k_t regs, ko = k_{t-1} regs (pending-update operand),
//   vpb = (M_{t-2} k_t)[i] (full, both halves), e_prev = e_{t-1},
//   ce_prev = g_{t-1} ? (k_{t-1}.k_t) : 0, g_prev = gate_{t-1},
//   M = M_{t-2}. Slot s holds k_s%3; DMA fills (t+2)%3.
// ---------------------------------------------------------------------------
__global__ __launch_bounds__(256, 1) void scan_kernel(
    const int* __restrict__ seq,
    const float* __restrict__ Htab2,
    const float* __restrict__ Wrp,
    const float* __restrict__ brp,
    float* __restrict__ rr)
{
  const int b     = blockIdx.x;
  const int tid   = threadIdx.x;
  const int i     = tid >> 1;
  const int half  = tid & 1;
  const int lane  = tid & 63;
  const int wv    = tid >> 6;
  const int iofs  = i + ((i >> 6) << 2);   // padded-row index of h[i]
  const int kbase = half * 68;             // float offset of own column half

  __shared__ int seq_s[LL];
  __shared__ __align__(16) float slots[3][RS];
  __shared__ __align__(16) float2 red2[3][4];   // {||e||^2, c} partials per wave
  __shared__ __align__(16) float r_s[128];
  __shared__ float p2_s[2][128];

  // prologue DMAs (k0 -> slot0, k1 -> slot1)
  {
    int t0 = seq[(size_t)b * LL + 0];
    int t1 = seq[(size_t)b * LL + 1];
    if (lane < 34) {
      dma16(Htab2 + (size_t)t0 * RS + lane * 4, &slots[0][0]);
      dma16(Htab2 + (size_t)t1 * RS + lane * 4, &slots[1][0]);
    }
  }
  for (int t = tid; t < LL; t += 256) seq_s[t] = seq[(size_t)b * LL + t];
  __syncthreads();   // full drain (incl. prologue DMAs) — once, at start

  f32x2 M2[32];
#pragma unroll
  for (int m = 0; m < 32; ++m) M2[m] = f32x2{0.f, 0.f};

  f32x2 kA[32], kB[32];
  float kiA, kkA, invA;
  float kiB = 0.f, kkB = 0.f, invB = 0.f;
  {
    const float4* kp = (const float4*)&slots[0][kbase];
#pragma unroll
    for (int m = 0; m < 16; ++m) {
      float4 tq = kp[m];
      kA[2 * m]     = f32x2{tq.x, tq.y};
      kA[2 * m + 1] = f32x2{tq.z, tq.w};
    }
    kiA = slots[0][iofs];
    float2 kv = *(const float2*)&slots[0][132];
    kkA = kv.x; invA = kv.y;
  }
#pragma unroll
  for (int m = 0; m < 32; ++m) kB[m] = f32x2{0.f, 0.f};  // k_{-1}: unused (g=0)

  // pipeline state
  float vpb = 0.f;       // (M_{t-2} k_t)[i], full
  float e_prev = 0.f;    // e_{t-1}[i]
  float ce_prev = 0.f;   // g_{t-1} ? k_{t-1}.k_t : 0
  int   g_prev = 0;      // gate_{t-1} (wave-uniform scalar)

  // mode 1: issue DMA k_{t+2}, wait vmcnt(1); mode 2: tail, vmcnt(0).
  auto step = [&](f32x2 (&kc)[32], float& ki_c, float& kk_c, float& inv_c,
                  f32x2 (&ko)[32], float& ki_o, float& kk_o, float& inv_o,
                  int t, int p, int sn, int sd, int mode) {
    if (mode == 1) {
      int tk = seq_s[t + 2];
      if (lane < 34)
        dma16(Htab2 + (size_t)tk * RS + lane * 4, &slots[sd][0]);
    }
    // pending update: M_{t-2} -> M_{t-1} (+= g e_{t-1} k_{t-1}^T), off the
    // gate->vp chain; skipped by uniform branch when gate was 0.
    if (g_prev) {
      f32x2 ev{e_prev, e_prev};
#pragma unroll
      for (int m = 0; m < 32; ++m) pkfma(M2[m], ev, ko[m]);
    }
    if (mode == 1) wait_vm1(); else wait_vm0();
    // refill ko <- k_{t+1} (scalar ki first: it feeds the c-tree pre-barrier)
    float ki_n = slots[sn][iofs];
    {
      const float4* kp = (const float4*)&slots[sn][kbase];
#pragma unroll
      for (int m = 0; m < 16; ++m) {
        float4 tq = kp[m];
        ko[2 * m]     = f32x2{tq.x, tq.y};
        ko[2 * m + 1] = f32x2{tq.z, tq.w};
      }
      float2 kv = *(const float2*)&slots[sn][132];
      kk_o = kv.x; inv_o = kv.y;
    }
    // vp_t via 1-FMA lookahead correction; e; interleaved reductions
    float vp = fmaf(ce_prev, e_prev, vpb);
    float e  = fmaf(-vp, inv_c, ki_c);
    float s  = e * e;                 // ||e||^2 partial (row i, dup per pair)
    float c1 = ki_c * ki_n;           // c_t = k_t.k_{t+1} partial (row i)
    s = dppadd<0x4E>(s);   c1 = dppadd<0x4E>(c1);
    s = dppadd<0x141>(s);  c1 = dppadd<0x141>(c1);
    s = dppadd<0x140>(s);  c1 = dppadd<0x140>(c1);
    s = dppadd<0x142>(s);  c1 = dppadd<0x142>(c1);
    s = dppadd<0x143>(s);  c1 = dppadd<0x143>(c1);
    if (lane == 63) red2[p][wv] = float2{s, c1};
    barrier_lgkm();                   // lgkmcnt(0)+s_barrier, NO vmcnt drain
    // issue red read, then hide its latency under next-step matvec:
    // vpb_next = (M_{t-1} k_{t+1})[i]
    float4 ra = ((const float4*)&red2[p][0])[0];
    float4 rb = ((const float4*)&red2[p][0])[1];
    f32x2 a0{0.f,0.f}, a1{0.f,0.f}, a2{0.f,0.f}, a3{0.f,0.f};
#pragma unroll
    for (int m = 0; m < 8; ++m) {
      pkfma(a0, ko[4 * m + 0], M2[4 * m + 0]);
      pkfma(a1, ko[4 * m + 1], M2[4 * m + 1]);
      pkfma(a2, ko[4 * m + 2], M2[4 * m + 2]);
      pkfma(a3, ko[4 * m + 3], M2[4 * m + 3]);
    }
    float nv = ((a0.x + a0.y) + (a1.x + a1.y)) + ((a2.x + a2.y) + (a3.x + a3.y));
    nv = dppadd<0xB1>(nv);
    float ne2 = (ra.x + ra.z) + (rb.x + rb.z);
    float cc  = (ra.y + ra.w) + (rb.y + rb.w);
    int g = ne2 > 0.16f * kk_c;       // ||e|| > 0.4*||v||  (squared form)
    g = __builtin_amdgcn_readfirstlane(g);
    // commit pipeline state
    g_prev  = g;
    e_prev  = e;
    ce_prev = g ? cc : 0.0f;
    vpb     = nv;
    ki_o    = ki_n;
  };

  // steps 0..2045 (2046 = 6*341); tail step 2046 with vmcnt(0).
  for (int t = 0; t < LL - 2; t += 6) {
    step(kA, kiA, kkA, invA, kB, kiB, kkB, invB, t + 0, 0, 1, 2, 1);
    step(kB, kiB, kkB, invB, kA, kiA, kkA, invA, t + 1, 1, 2, 0, 1);
    step(kA, kiA, kkA, invA, kB, kiB, kkB, invB, t + 2, 2, 0, 1, 1);
    step(kB, kiB, kkB, invB, kA, kiA, kkA, invA, t + 3, 0, 1, 2, 1);
    step(kA, kiA, kkA, invA, kB, kiB, kkB, invB, t + 4, 1, 2, 0, 1);
    step(kB, kiB, kkB, invB, kA, kiA, kkA, invA, t + 5, 2, 0, 1, 1);
  }
  step(kA, kiA, kkA, invA, kB, kiB, kkB, invB, LL - 2, 0, 1, 2, 2);

  // r = M_2046 @ k_2047 = (M_2045 k_2047) + g_2046 (k_2046.k_2047) e_2046
  //   = vpb + ce_prev * e_prev  (tail step's matvec/reduction outputs)
  {
    float rres = fmaf(ce_prev, e_prev, vpb);
    if (half == 0) r_s[i] = rres;
  }
  __syncthreads();

  // rr[b,:] = r @ Wrp + brp
  const int j  = tid & 127;
  const int h2 = tid >> 7;
  float pac[2] = {0.f, 0.f};
#pragma unroll
  for (int m = 0; m < 64; ++m) {
    pac[m & 1] = fmaf(r_s[h2 * 64 + m],
                      Wrp[(size_t)(h2 * 64 + m) * 128 + j], pac[m & 1]);
  }
  p2_s[h2][j] = pac[0] + pac[1];
  __syncthreads();
  if (tid < 128) {
    rr[(size_t)b * 128 + tid] = p2_s[0][tid] + p2_s[1][tid] + brp[tid];
  }
}

// ---------------------------------------------------------------------------
// Kernel C: out[b,v] = rr[b,:] @ Wout[:,v] + bout[v]  (unchanged)
// ---------------------------------------------------------------------------
__global__ __launch_bounds__(256, 1) void out_kernel(
    const float* __restrict__ rr,
    const float* __restrict__ Wout,
    const float* __restrict__ bout,
    float* __restrict__ out)
{
  const int tid = threadIdx.x;
  const int v = blockIdx.x * 64 + (tid & 63);
  const int bg = tid >> 6;
  const int b0 = blockIdx.y * 64;

  __shared__ float4 rs4[64][32];
  for (int idx = tid; idx < 2048; idx += 256) {
    int bb = idx >> 5, q = idx & 31;
    rs4[bb][q] = ((const float4*)rr)[(size_t)(b0 + bb) * 32 + q];
  }
  __syncthreads();

  float acc[16];
#pragma unroll
  for (int m = 0; m < 16; ++m) acc[m] = 0.0f;

  for (int h4 = 0; h4 < 32; ++h4) {
    float w0 = Wout[(size_t)(4 * h4 + 0) * VV + v];
    float w1 = Wout[(size_t)(4 * h4 + 1) * VV + v];
    float w2 = Wout[(size_t)(4 * h4 + 2) * VV + v];
    float w3 = Wout[(size_t)(4 * h4 + 3) * VV + v];
#pragma unroll
    for (int m = 0; m < 16; ++m) {
      float4 rv = rs4[bg * 16 + m][h4];
      float t = rv.x * w0;
      t = fmaf(rv.y, w1, t);
      t = fmaf(rv.z, w2, t);
      t = fmaf(rv.w, w3, t);
      acc[m] += t;
    }
  }
  float bo = bout[v];
#pragma unroll
  for (int m = 0; m < 16; ++m) {
    out[(size_t)(b0 + bg * 16 + m) * VV + v] = acc[m] + bo;
  }
}

// ---------------------------------------------------------------------------
extern "C" void kernel_launch(void* const* d_in, const int* in_sizes, int n_in,
                              void* d_out, int out_size, void* d_ws, size_t ws_size,
                              hipStream_t stream)
{
  const int* seq      = (const int*)d_in[0];
  const float* embed  = (const float*)d_in[1];
  const float* W1     = (const float*)d_in[2];
  const float* b1     = (const float*)d_in[3];
  const float* W2     = (const float*)d_in[4];
  const float* b2     = (const float*)d_in[5];
  const float* gamma  = (const float*)d_in[6];
  const float* beta   = (const float*)d_in[7];
  const float* Wrp    = (const float*)d_in[8];
  const float* brp    = (const float*)d_in[9];
  const float* Wout   = (const float*)d_in[10];
  const float* bout   = (const float*)d_in[11];
  float* out          = (float*)d_out;

  char* ws = (char*)d_ws;
  float* Htab2 = (float*)ws;                         // 32000*136*4 = 17,408,000 B
  float* rr    = (float*)(ws + 17408000);            //    131,072 B

  hipLaunchKernelGGL(build_htab_kernel, dim3(256), dim3(256), 0, stream,
                     embed, W1, b1, W2, b2, gamma, beta, Htab2);
  hipLaunchKernelGGL(scan_kernel, dim3(BB), dim3(256), 0, stream,
                     seq, Htab2, Wrp, brp, rr);
  hipLaunchKernelGGL(out_kernel, dim3(VV / 64, 4), dim3(256), 0, stream,
                     rr, Wout, bout, out);
}

// Round 2
// 1467.311 us; speedup vs baseline: 1.0991x; 1.0991x over previous
//
#include <hip/hip_runtime.h>
#include <hip/hip_bf16.h>

// B=256, L=2048, H=128, V=32000, THR=0.4, LN_EPS=1e-5. All fp32.
// Htab2 row (RS=136 floats, padded for LDS bank-disjointness):
//   [0:64)=h[0..63], [64:68)=pad, [68:132)=h[64..127], [132]=kk, [133]=inv.
// Scan v3: v1 step structure (matvec pre-barrier, unconditional update,
// vmcnt wait post-barrier) + 4-slot LDS k-ring with 3-step DMA lead and
// counted s_waitcnt vmcnt(3) so random-row HBM latency (~900+cy, 44% miss)
// is fully hidden. 12-step unroll keeps slot/red-phase indices literal.

#define BB 256
#define LL 2048
#define HH 128
#define VV 32000
#define RS 136

typedef float f32x2 __attribute__((ext_vector_type(2)));

__device__ __forceinline__ void dma16(const float* g, float* l) {
  __builtin_amdgcn_global_load_lds(
      (const __attribute__((address_space(1))) void*)g,
      (__attribute__((address_space(3))) void*)l,
      16, 0, 0);
}

template <int CTRL>
__device__ __forceinline__ float dppadd(float x) {
  int y = __builtin_amdgcn_update_dpp(0, __float_as_int(x), CTRL, 0xF, 0xF, true);
  return x + __int_as_float(y);
}

// d = a*b + d  (packed 2x fp32)
__device__ __forceinline__ void pkfma(f32x2& d, f32x2 a, f32x2 b) {
  asm("v_pk_fma_f32 %0, %1, %2, %0" : "+v"(d) : "v"(a), "v"(b));
}

__device__ __forceinline__ void barrier_lgkm() {
  asm volatile("s_waitcnt lgkmcnt(0)\n\ts_barrier" ::: "memory");
}
__device__ __forceinline__ void wait_vmN(int n) {
  // call sites pass literals inside force-inlined unrolled code -> folds
  if (n == 3)      asm volatile("s_waitcnt vmcnt(3)" ::: "memory");
  else if (n == 2) asm volatile("s_waitcnt vmcnt(2)" ::: "memory");
  else if (n == 1) asm volatile("s_waitcnt vmcnt(1)" ::: "memory");
  else             asm volatile("s_waitcnt vmcnt(0)" ::: "memory");
}

// ---------------------------------------------------------------------------
// Kernel A: Htab2 row = LN(e + relu(e@W1+b1)@W2 + b2) (+ kk, inv), padded.
// (unchanged from verified baseline)
// ---------------------------------------------------------------------------
__global__ __launch_bounds__(256, 1) void build_htab_kernel(
    const float* __restrict__ embed,
    const float* __restrict__ W1,
    const float* __restrict__ b1,
    const float* __restrict__ W2,
    const float* __restrict__ b2,
    const float* __restrict__ gamma,
    const float* __restrict__ beta,
    float* __restrict__ Htab2)
{
  const int tid = threadIdx.x;
  const int j   = tid & 127;
  const int h2  = tid >> 7;

  float w1r[128];
#pragma unroll
  for (int m = 0; m < 128; ++m) w1r[m] = W1[m * 256 + tid];

  const float b1n = b1[tid];
  const float b2j = b2[j];
  const float gj  = gamma[j];
  const float bj  = beta[j];

  __shared__ __align__(16) float4 w2q[64][128];   // 128 KiB
  __shared__ __align__(16) float e_s[128];
  __shared__ __align__(16) float a_s[256];
  __shared__ float p_s[2][128];
  __shared__ float red[8];

  for (int idx = tid; idx < 8192; idx += 256) {
    int n4 = idx >> 7, jj = idx & 127;
    float4 w;
    w.x = W2[(size_t)(4 * n4 + 0) * 128 + jj];
    w.y = W2[(size_t)(4 * n4 + 1) * 128 + jj];
    w.z = W2[(size_t)(4 * n4 + 2) * 128 + jj];
    w.w = W2[(size_t)(4 * n4 + 3) * 128 + jj];
    w2q[n4][jj] = w;
  }
  __syncthreads();

  for (int v = blockIdx.x; v < VV; v += gridDim.x) {
    if (tid < 128) e_s[tid] = embed[(size_t)v * 128 + tid];
    __syncthreads();

    float acc[4] = {b1n, 0.f, 0.f, 0.f};
#pragma unroll
    for (int q = 0; q < 32; ++q) {
      float4 ev = *(const float4*)&e_s[4 * q];
      float t = ev.x * w1r[4 * q + 0];
      t = fmaf(ev.y, w1r[4 * q + 1], t);
      t = fmaf(ev.z, w1r[4 * q + 2], t);
      t = fmaf(ev.w, w1r[4 * q + 3], t);
      acc[q & 3] += t;
    }
    float a = fmaxf((acc[0] + acc[1]) + (acc[2] + acc[3]), 0.0f);
    a_s[tid] = a;
    __syncthreads();

    float p0 = 0.f, p1 = 0.f, p2v = 0.f, p3 = 0.f;
#pragma unroll
    for (int q = 0; q < 32; ++q) {
      int n4 = h2 * 32 + q;
      float4 av = *(const float4*)&a_s[4 * n4];
      float4 wq = w2q[n4][j];
      p0 = fmaf(av.x, wq.x, p0);
      p1 = fmaf(av.y, wq.y, p1);
      p2v = fmaf(av.z, wq.z, p2v);
      p3 = fmaf(av.w, wq.w, p3);
    }
    p_s[h2][j] = (p0 + p1) + (p2v + p3);
    __syncthreads();

    float y = 0.0f;
    if (tid < 128) {
      float ff = p_s[0][tid] + p_s[1][tid] + b2j;
      y = e_s[tid] + ff;
    }
    float s1 = y, s2 = y * y;
    s1 = dppadd<0xB1>(s1);  s2 = dppadd<0xB1>(s2);
    s1 = dppadd<0x4E>(s1);  s2 = dppadd<0x4E>(s2);
    s1 = dppadd<0x141>(s1); s2 = dppadd<0x141>(s2);
    s1 = dppadd<0x140>(s1); s2 = dppadd<0x140>(s2);
    s1 = dppadd<0x142>(s1); s2 = dppadd<0x142>(s2);
    s1 = dppadd<0x143>(s1); s2 = dppadd<0x143>(s2);
    if (tid < 128 && (tid & 63) == 63) {
      red[tid >> 6] = s1;
      red[2 + (tid >> 6)] = s2;
    }
    __syncthreads();
    float mu = (red[0] + red[1]) * (1.0f / 128.0f);
    float ms = (red[2] + red[3]) * (1.0f / 128.0f);
    float var = ms - mu * mu;
    float hv = 0.0f;
    if (tid < 128) {
      float dy = y - mu;
      hv = dy * (1.0f / sqrtf(var + 1e-5f)) * gj + bj;
      int ofs = tid + ((tid >> 6) << 2);           // padded layout
      Htab2[(size_t)v * RS + ofs] = hv;
    }
    float q2 = hv * hv;
    q2 = dppadd<0xB1>(q2);
    q2 = dppadd<0x4E>(q2);
    q2 = dppadd<0x141>(q2);
    q2 = dppadd<0x140>(q2);
    q2 = dppadd<0x142>(q2);
    q2 = dppadd<0x143>(q2);
    if (tid < 128 && (tid & 63) == 63) red[4 + (tid >> 6)] = q2;
    __syncthreads();
    if (tid == 0) {
      float kk = red[4] + red[5];
      Htab2[(size_t)v * RS + 132] = kk;
      Htab2[(size_t)v * RS + 133] = 1.0f / (kk + 1e-6f);
    }
    __syncthreads();
  }
}

// ---------------------------------------------------------------------------
// Kernel B: per-batch scan. 256 blocks x 256 threads, 1 block/CU.
// Thread (i=tid>>1, half=tid&1) owns M[i][64*half..+63] as 32 f32x2.
// Slot t&3 holds k_t; step t issues DMA k_{t+4} -> slot t&3 (k_t's regs were
// refilled at step t-1, so the slot is dead). Post-barrier wait vmcnt(3)
// retires exactly the oldest outstanding load = k_{t+1}.
// ---------------------------------------------------------------------------
__global__ __launch_bounds__(256, 1) void scan_kernel(
    const int* __restrict__ seq,
    const float* __restrict__ Htab2,
    const float* __restrict__ Wrp,
    const float* __restrict__ brp,
    float* __restrict__ rr)
{
  const int b     = blockIdx.x;
  const int tid   = threadIdx.x;
  const int i     = tid >> 1;
  const int half  = tid & 1;
  const int lane  = tid & 63;
  const int wv    = tid >> 6;
  const int iofs  = i + ((i >> 6) << 2);   // padded-row index of h[i]
  const int kbase = half * 68;             // float offset of own column half

  __shared__ int seq_s[LL];
  __shared__ __align__(16) float slots[4][RS];
  __shared__ __align__(16) float red_s[3][4];
  __shared__ __align__(16) float r_s[128];
  __shared__ float p2_s[2][128];

  // prologue DMAs: k0..k3 -> slots 0..3
  {
    int t0 = seq[(size_t)b * LL + 0];
    int t1 = seq[(size_t)b * LL + 1];
    int t2 = seq[(size_t)b * LL + 2];
    int t3 = seq[(size_t)b * LL + 3];
    if (lane < 34) {
      dma16(Htab2 + (size_t)t0 * RS + lane * 4, &slots[0][0]);
      dma16(Htab2 + (size_t)t1 * RS + lane * 4, &slots[1][0]);
      dma16(Htab2 + (size_t)t2 * RS + lane * 4, &slots[2][0]);
      dma16(Htab2 + (size_t)t3 * RS + lane * 4, &slots[3][0]);
    }
  }
  for (int t = tid; t < LL; t += 256) seq_s[t] = seq[(size_t)b * LL + t];
  __syncthreads();   // full drain (incl. prologue DMAs) — once, at start

  f32x2 M2[32];
#pragma unroll
  for (int m = 0; m < 32; ++m) M2[m] = f32x2{0.f, 0.f};

  f32x2 kA[32], kB[32];
  float kiA, kkA, invA, kiB, kkB, invB;
  {
    const float4* kp = (const float4*)&slots[0][kbase];
#pragma unroll
    for (int m = 0; m < 16; ++m) {
      float4 tq = kp[m];
      kA[2 * m]     = f32x2{tq.x, tq.y};
      kA[2 * m + 1] = f32x2{tq.z, tq.w};
    }
    kiA = slots[0][iofs];
    float2 kv = *(const float2*)&slots[0][132];
    kkA = kv.x; invA = kv.y;
#pragma unroll
    for (int m = 0; m < 32; ++m) asm volatile("" : "+v"(kA[m]));
    asm volatile("" : "+v"(kiA), "+v"(kkA), "+v"(invA));
  }

  // nwait==3: issue DMA k_{t+4} into slot sd, wait vmcnt(3).
  // nwait<3 : tail, no issue, wait vmcnt(nwait).
  auto step = [&](f32x2 (&kc)[32], float ki_c, float kk_c, float inv_c,
                  f32x2 (&kn)[32], float& ki_n, float& kk_n, float& inv_n,
                  int t, int p, int sn, int sd, int nwait) {
    if (nwait == 3) {
      int tk = seq_s[t + 4];
      if (lane < 34)
        dma16(Htab2 + (size_t)tk * RS + lane * 4, &slots[sd][0]);
    }
    // vp over own 64 columns (packed)
    f32x2 a0{0.f,0.f}, a1{0.f,0.f}, a2{0.f,0.f}, a3{0.f,0.f};
#pragma unroll
    for (int m = 0; m < 8; ++m) {
      pkfma(a0, kc[4 * m + 0], M2[4 * m + 0]);
      pkfma(a1, kc[4 * m + 1], M2[4 * m + 1]);
      pkfma(a2, kc[4 * m + 2], M2[4 * m + 2]);
      pkfma(a3, kc[4 * m + 3], M2[4 * m + 3]);
    }
    float vp = ((a0.x + a0.y) + (a1.x + a1.y)) + ((a2.x + a2.y) + (a3.x + a3.y));
    vp = dppadd<0xB1>(vp);                 // pair halves (xor1)
    float e = fmaf(-vp, inv_c, ki_c);
    // ||e||^2 (each distinct row once; ne2 == ||e||^2)
    float s = e * e;
    s = dppadd<0x4E>(s);
    s = dppadd<0x141>(s);
    s = dppadd<0x140>(s);
    s = dppadd<0x142>(s);
    s = dppadd<0x143>(s);
    if (lane == 63) red_s[p][wv] = s;
    barrier_lgkm();                        // lgkmcnt(0)+s_barrier, NO vmcnt drain

    float4 rv = *(const float4*)red_s[p];  // issue early: latency overlaps refill
    wait_vmN(nwait);
    {                                      // refill k_{t+1} -> kn (consumed next step)
      const float4* kp = (const float4*)&slots[sn][kbase];
#pragma unroll
      for (int m = 0; m < 16; ++m) {
        float4 tq = kp[m];
        kn[2 * m]     = f32x2{tq.x, tq.y};
        kn[2 * m + 1] = f32x2{tq.z, tq.w};
      }
      ki_n = slots[sn][iofs];
      float2 kv = *(const float2*)&slots[sn][132];
      kk_n = kv.x; inv_n = kv.y;
    }
    float ne2 = (rv.x + rv.y) + (rv.z + rv.w);
    float ge = (ne2 > 0.16f * kk_c) ? e : 0.0f;   // ||e|| > 0.4*||v||
    f32x2 ev{ge, ge};
#pragma unroll
    for (int m = 0; m < 32; ++m) pkfma(M2[m], ev, kc[m]);
    // pin kn AFTER the update so its loads hide under red-read + update
#pragma unroll
    for (int m = 0; m < 32; ++m) asm volatile("" : "+v"(kn[m]));
    asm volatile("" : "+v"(ki_n), "+v"(kk_n), "+v"(inv_n));
  };

  // steps 0..2039 (2040 = 12*170). Slot t&3 holds k_t; DMA fills (t+4)&3.
  for (int t = 0; t < 2040; t += 12) {
    step(kA, kiA, kkA, invA, kB, kiB, kkB, invB, t + 0,  0, 1, 0, 3);
    step(kB, kiB, kkB, invB, kA, kiA, kkA, invA, t + 1,  1, 2, 1, 3);
    step(kA, kiA, kkA, invA, kB, kiB, kkB, invB, t + 2,  2, 3, 2, 3);
    step(kB, kiB, kkB, invB, kA, kiA, kkA, invA, t + 3,  0, 0, 3, 3);
    step(kA, kiA, kkA, invA, kB, kiB, kkB, invB, t + 4,  1, 1, 0, 3);
    step(kB, kiB, kkB, invB, kA, kiA, kkA, invA, t + 5,  2, 2, 1, 3);
    step(kA, kiA, kkA, invA, kB, kiB, kkB, invB, t + 6,  0, 3, 2, 3);
    step(kB, kiB, kkB, invB, kA, kiA, kkA, invA, t + 7,  1, 0, 3, 3);
    step(kA, kiA, kkA, invA, kB, kiB, kkB, invB, t + 8,  2, 1, 0, 3);
    step(kB, kiB, kkB, invB, kA, kiA, kkA, invA, t + 9,  0, 2, 1, 3);
    step(kA, kiA, kkA, invA, kB, kiB, kkB, invB, t + 10, 1, 3, 2, 3);
    step(kB, kiB, kkB, invB, kA, kiA, kkA, invA, t + 11, 2, 0, 3, 3);
  }
  // tail: steps 2040..2046, drain vmcnt 3 -> 0
  step(kA, kiA, kkA, invA, kB, kiB, kkB, invB, 2040, 0, 1, 0, 3);
  step(kB, kiB, kkB, invB, kA, kiA, kkA, invA, 2041, 1, 2, 1, 3);
  step(kA, kiA, kkA, invA, kB, kiB, kkB, invB, 2042, 2, 3, 2, 3);
  step(kB, kiB, kkB, invB, kA, kiA, kkA, invA, 2043, 0, 0, 3, 3);
  step(kA, kiA, kkA, invA, kB, kiB, kkB, invB, 2044, 1, 1, 0, 2);
  step(kB, kiB, kkB, invB, kA, kiA, kkA, invA, 2045, 2, 2, 1, 1);
  step(kA, kiA, kkA, invA, kB, kiB, kkB, invB, 2046, 0, 3, 2, 0);

  // r = M_fin @ h(seq[b, L-1])  (kB = k_2047)
  {
    f32x2 a0{0.f,0.f}, a1{0.f,0.f}, a2{0.f,0.f}, a3{0.f,0.f};
#pragma unroll
    for (int m = 0; m < 8; ++m) {
      pkfma(a0, kB[4 * m + 0], M2[4 * m + 0]);
      pkfma(a1, kB[4 * m + 1], M2[4 * m + 1]);
      pkfma(a2, kB[4 * m + 2], M2[4 * m + 2]);
      pkfma(a3, kB[4 * m + 3], M2[4 * m + 3]);
    }
    float vp = ((a0.x + a0.y) + (a1.x + a1.y)) + ((a2.x + a2.y) + (a3.x + a3.y));
    vp = dppadd<0xB1>(vp);
    if (half == 0) r_s[i] = vp;
  }
  __syncthreads();

  // rr[b,:] = r @ Wrp + brp
  const int j  = tid & 127;
  const int h2 = tid >> 7;
  float pac[2] = {0.f, 0.f};
#pragma unroll
  for (int m = 0; m < 64; ++m) {
    pac[m & 1] = fmaf(r_s[h2 * 64 + m],
                      Wrp[(size_t)(h2 * 64 + m) * 128 + j], pac[m & 1]);
  }
  p2_s[h2][j] = pac[0] + pac[1];
  __syncthreads();
  if (tid < 128) {
    rr[(size_t)b * 128 + tid] = p2_s[0][tid] + p2_s[1][tid] + brp[tid];
  }
}

// ---------------------------------------------------------------------------
// Kernel C: out[b,v] = rr[b,:] @ Wout[:,v] + bout[v]  (unchanged)
// ---------------------------------------------------------------------------
__global__ __launch_bounds__(256, 1) void out_kernel(
    const float* __restrict__ rr,
    const float* __restrict__ Wout,
    const float* __restrict__ bout,
    float* __restrict__ out)
{
  const int tid = threadIdx.x;
  const int v = blockIdx.x * 64 + (tid & 63);
  const int bg = tid >> 6;
  const int b0 = blockIdx.y * 64;

  __shared__ float4 rs4[64][32];
  for (int idx = tid; idx < 2048; idx += 256) {
    int bb = idx >> 5, q = idx & 31;
    rs4[bb][q] = ((const float4*)rr)[(size_t)(b0 + bb) * 32 + q];
  }
  __syncthreads();

  float acc[16];
#pragma unroll
  for (int m = 0; m < 16; ++m) acc[m] = 0.0f;

  for (int h4 = 0; h4 < 32; ++h4) {
    float w0 = Wout[(size_t)(4 * h4 + 0) * VV + v];
    float w1 = Wout[(size_t)(4 * h4 + 1) * VV + v];
    float w2 = Wout[(size_t)(4 * h4 + 2) * VV + v];
    float w3 = Wout[(size_t)(4 * h4 + 3) * VV + v];
#pragma unroll
    for (int m = 0; m < 16; ++m) {
      float4 rv = rs4[bg * 16 + m][h4];
      float t = rv.x * w0;
      t = fmaf(rv.y, w1, t);
      t = fmaf(rv.z, w2, t);
      t = fmaf(rv.w, w3, t);
      acc[m] += t;
    }
  }
  float bo = bout[v];
#pragma unroll
  for (int m = 0; m < 16; ++m) {
    out[(size_t)(b0 + bg * 16 + m) * VV + v] = acc[m] + bo;
  }
}

// ---------------------------------------------------------------------------
extern "C" void kernel_launch(void* const* d_in, const int* in_sizes, int n_in,
                              void* d_out, int out_size, void* d_ws, size_t ws_size,
                              hipStream_t stream)
{
  const int* seq      = (const int*)d_in[0];
  const float* embed  = (const float*)d_in[1];
  const float* W1     = (const float*)d_in[2];
  const float* b1     = (const float*)d_in[3];
  const float* W2     = (const float*)d_in[4];
  const float* b2     = (const float*)d_in[5];
  const float* gamma  = (const float*)d_in[6];
  const float* beta   = (const float*)d_in[7];
  const float* Wrp    = (const float*)d_in[8];
  const float* brp    = (const float*)d_in[9];
  const float* Wout   = (const float*)d_in[10];
  const float* bout   = (const float*)d_in[11];
  float* out          = (float*)d_out;

  char* ws = (char*)d_ws;
  float* Htab2 = (float*)ws;                         // 32000*136*4 = 17,408,000 B
  float* rr    = (float*)(ws + 17408000);            //    131,072 B

  hipLaunchKernelGGL(build_htab_kernel, dim3(256), dim3(256), 0, stream,
                     embed, W1, b1, W2, b2, gamma, beta, Htab2);
  hipLaunchKernelGGL(scan_kernel, dim3(BB), dim3(256), 0, stream,
                     seq, Htab2, Wrp, brp, rr);
  hipLaunchKernelGGL(out_kernel, dim3(VV / 64, 4), dim3(256), 0, stream,
                     rr, Wout, bout, out);
}

// Round 3
// 1456.377 us; speedup vs baseline: 1.1074x; 1.0075x over previous
//
#include <hip/hip_runtime.h>
#include <hip/hip_bf16.h>

// B=256, L=2048, H=128, V=32000, THR=0.4, LN_EPS=1e-5. All fp32.
// Htab2 row (RS=136 floats, padded for LDS bank-disjointness):
//   [0:64)=h[0..63], [64:68)=pad, [68:132)=h[64..127], [132]=kk, [133]=inv.
// Scan v4: 512 threads/block (2 waves/SIMD) to hide the serial-chain latency
// that v1/v3 exposed at 1 wave/SIMD. Thread (i=tid>>2, q=tid&3) owns 32 cols
// of row i. vp quad-sum = dpp 0xB1+0x4E; ||e||^2 tree drops to 4 levels
// (e quad-replicated -> each row counted once). 8-slot LDS k-ring, lead-4
// DMA, counted vmcnt(3); step structure otherwise identical to v1.

#define BB 256
#define LL 2048
#define HH 128
#define VV 32000
#define RS 136

typedef float f32x2 __attribute__((ext_vector_type(2)));

__device__ __forceinline__ void dma16(const float* g, float* l) {
  __builtin_amdgcn_global_load_lds(
      (const __attribute__((address_space(1))) void*)g,
      (__attribute__((address_space(3))) void*)l,
      16, 0, 0);
}

template <int CTRL>
__device__ __forceinline__ float dppadd(float x) {
  int y = __builtin_amdgcn_update_dpp(0, __float_as_int(x), CTRL, 0xF, 0xF, true);
  return x + __int_as_float(y);
}

// d = a*b + d  (packed 2x fp32)
__device__ __forceinline__ void pkfma(f32x2& d, f32x2 a, f32x2 b) {
  asm("v_pk_fma_f32 %0, %1, %2, %0" : "+v"(d) : "v"(a), "v"(b));
}

__device__ __forceinline__ void barrier_lgkm() {
  asm volatile("s_waitcnt lgkmcnt(0)\n\ts_barrier" ::: "memory");
}
__device__ __forceinline__ void wait_vmN(int n) {
  if (n == 3)      asm volatile("s_waitcnt vmcnt(3)" ::: "memory");
  else if (n == 2) asm volatile("s_waitcnt vmcnt(2)" ::: "memory");
  else if (n == 1) asm volatile("s_waitcnt vmcnt(1)" ::: "memory");
  else             asm volatile("s_waitcnt vmcnt(0)" ::: "memory");
}

// ---------------------------------------------------------------------------
// Kernel A: Htab2 row = LN(e + relu(e@W1+b1)@W2 + b2) (+ kk, inv), padded.
// (unchanged from verified baseline)
// ---------------------------------------------------------------------------
__global__ __launch_bounds__(256, 1) void build_htab_kernel(
    const float* __restrict__ embed,
    const float* __restrict__ W1,
    const float* __restrict__ b1,
    const float* __restrict__ W2,
    const float* __restrict__ b2,
    const float* __restrict__ gamma,
    const float* __restrict__ beta,
    float* __restrict__ Htab2)
{
  const int tid = threadIdx.x;
  const int j   = tid & 127;
  const int h2  = tid >> 7;

  float w1r[128];
#pragma unroll
  for (int m = 0; m < 128; ++m) w1r[m] = W1[m * 256 + tid];

  const float b1n = b1[tid];
  const float b2j = b2[j];
  const float gj  = gamma[j];
  const float bj  = beta[j];

  __shared__ __align__(16) float4 w2q[64][128];   // 128 KiB
  __shared__ __align__(16) float e_s[128];
  __shared__ __align__(16) float a_s[256];
  __shared__ float p_s[2][128];
  __shared__ float red[8];

  for (int idx = tid; idx < 8192; idx += 256) {
    int n4 = idx >> 7, jj = idx & 127;
    float4 w;
    w.x = W2[(size_t)(4 * n4 + 0) * 128 + jj];
    w.y = W2[(size_t)(4 * n4 + 1) * 128 + jj];
    w.z = W2[(size_t)(4 * n4 + 2) * 128 + jj];
    w.w = W2[(size_t)(4 * n4 + 3) * 128 + jj];
    w2q[n4][jj] = w;
  }
  __syncthreads();

  for (int v = blockIdx.x; v < VV; v += gridDim.x) {
    if (tid < 128) e_s[tid] = embed[(size_t)v * 128 + tid];
    __syncthreads();

    float acc[4] = {b1n, 0.f, 0.f, 0.f};
#pragma unroll
    for (int q = 0; q < 32; ++q) {
      float4 ev = *(const float4*)&e_s[4 * q];
      float t = ev.x * w1r[4 * q + 0];
      t = fmaf(ev.y, w1r[4 * q + 1], t);
      t = fmaf(ev.z, w1r[4 * q + 2], t);
      t = fmaf(ev.w, w1r[4 * q + 3], t);
      acc[q & 3] += t;
    }
    float a = fmaxf((acc[0] + acc[1]) + (acc[2] + acc[3]), 0.0f);
    a_s[tid] = a;
    __syncthreads();

    float p0 = 0.f, p1 = 0.f, p2v = 0.f, p3 = 0.f;
#pragma unroll
    for (int q = 0; q < 32; ++q) {
      int n4 = h2 * 32 + q;
      float4 av = *(const float4*)&a_s[4 * n4];
      float4 wq = w2q[n4][j];
      p0 = fmaf(av.x, wq.x, p0);
      p1 = fmaf(av.y, wq.y, p1);
      p2v = fmaf(av.z, wq.z, p2v);
      p3 = fmaf(av.w, wq.w, p3);
    }
    p_s[h2][j] = (p0 + p1) + (p2v + p3);
    __syncthreads();

    float y = 0.0f;
    if (tid < 128) {
      float ff = p_s[0][tid] + p_s[1][tid] + b2j;
      y = e_s[tid] + ff;
    }
    float s1 = y, s2 = y * y;
    s1 = dppadd<0xB1>(s1);  s2 = dppadd<0xB1>(s2);
    s1 = dppadd<0x4E>(s1);  s2 = dppadd<0x4E>(s2);
    s1 = dppadd<0x141>(s1); s2 = dppadd<0x141>(s2);
    s1 = dppadd<0x140>(s1); s2 = dppadd<0x140>(s2);
    s1 = dppadd<0x142>(s1); s2 = dppadd<0x142>(s2);
    s1 = dppadd<0x143>(s1); s2 = dppadd<0x143>(s2);
    if (tid < 128 && (tid & 63) == 63) {
      red[tid >> 6] = s1;
      red[2 + (tid >> 6)] = s2;
    }
    __syncthreads();
    float mu = (red[0] + red[1]) * (1.0f / 128.0f);
    float ms = (red[2] + red[3]) * (1.0f / 128.0f);
    float var = ms - mu * mu;
    float hv = 0.0f;
    if (tid < 128) {
      float dy = y - mu;
      hv = dy * (1.0f / sqrtf(var + 1e-5f)) * gj + bj;
      int ofs = tid + ((tid >> 6) << 2);           // padded layout
      Htab2[(size_t)v * RS + ofs] = hv;
    }
    float q2 = hv * hv;
    q2 = dppadd<0xB1>(q2);
    q2 = dppadd<0x4E>(q2);
    q2 = dppadd<0x141>(q2);
    q2 = dppadd<0x140>(q2);
    q2 = dppadd<0x142>(q2);
    q2 = dppadd<0x143>(q2);
    if (tid < 128 && (tid & 63) == 63) red[4 + (tid >> 6)] = q2;
    __syncthreads();
    if (tid == 0) {
      float kk = red[4] + red[5];
      Htab2[(size_t)v * RS + 132] = kk;
      Htab2[(size_t)v * RS + 133] = 1.0f / (kk + 1e-6f);
    }
    __syncthreads();
  }
}

// ---------------------------------------------------------------------------
// Kernel B: per-batch scan. 256 blocks x 512 threads (8 waves, 2/SIMD).
// Thread (i=tid>>2, q=tid&3) owns M[i][32q..32q+32) as 16 f32x2.
// Slot t&7 holds k_t; step t issues DMA k_{t+4} -> slot (t+4)&7 (last read
// 4 barriers earlier -> race-free). Post-barrier vmcnt(3) retires exactly
// the DMA for k_{t+1}, which the refill then reads.
// ---------------------------------------------------------------------------
__global__ __launch_bounds__(512, 2) void scan_kernel(
    const int* __restrict__ seq,
    const float* __restrict__ Htab2,
    const float* __restrict__ Wrp,
    const float* __restrict__ brp,
    float* __restrict__ rr)
{
  const int b     = blockIdx.x;
  const int tid   = threadIdx.x;
  const int i     = tid >> 2;              // row 0..127
  const int q     = tid & 3;               // column quarter
  const int lane  = tid & 63;
  const int wv    = tid >> 6;              // wave 0..7
  const int iofs  = i + ((i >> 6) << 2);   // padded-row index of h[i]
  const int kbase = (q & 1) * 32 + (q >> 1) * 68;  // float offset of own 32 cols

  __shared__ int seq_s[LL];
  __shared__ __align__(16) float slots[8][RS];
  __shared__ __align__(16) float red_s[4][8];
  __shared__ __align__(16) float r_s[128];
  __shared__ float p2_s[4][128];

  // prologue DMAs: k0..k3 -> slots 0..3 (every wave issues its own copy)
  {
    int t0 = seq[(size_t)b * LL + 0];
    int t1 = seq[(size_t)b * LL + 1];
    int t2 = seq[(size_t)b * LL + 2];
    int t3 = seq[(size_t)b * LL + 3];
    if (lane < 34) {
      dma16(Htab2 + (size_t)t0 * RS + lane * 4, &slots[0][0]);
      dma16(Htab2 + (size_t)t1 * RS + lane * 4, &slots[1][0]);
      dma16(Htab2 + (size_t)t2 * RS + lane * 4, &slots[2][0]);
      dma16(Htab2 + (size_t)t3 * RS + lane * 4, &slots[3][0]);
    }
  }
  for (int t = tid; t < LL; t += 512) seq_s[t] = seq[(size_t)b * LL + t];
  __syncthreads();   // full drain (incl. prologue DMAs) — once, at start

  f32x2 M2[16];
#pragma unroll
  for (int m = 0; m < 16; ++m) M2[m] = f32x2{0.f, 0.f};

  f32x2 kA[16], kB[16];
  float kiA, kkA, invA, kiB, kkB, invB;
  {
    const float4* kp = (const float4*)&slots[0][kbase];
#pragma unroll
    for (int m = 0; m < 8; ++m) {
      float4 tq = kp[m];
      kA[2 * m]     = f32x2{tq.x, tq.y};
      kA[2 * m + 1] = f32x2{tq.z, tq.w};
    }
    kiA = slots[0][iofs];
    float2 kv = *(const float2*)&slots[0][132];
    kkA = kv.x; invA = kv.y;
#pragma unroll
    for (int m = 0; m < 16; ++m) asm volatile("" : "+v"(kA[m]));
    asm volatile("" : "+v"(kiA), "+v"(kkA), "+v"(invA));
  }

  // nwait==3: issue DMA k_{t+4} into slot sd, wait vmcnt(3).
  // nwait<3 : tail, no issue, wait vmcnt(nwait).
  auto step = [&](f32x2 (&kc)[16], float ki_c, float kk_c, float inv_c,
                  f32x2 (&kn)[16], float& ki_n, float& kk_n, float& inv_n,
                  int t, int p, int sn, int sd, int nwait) {
    if (nwait == 3) {
      int tk = seq_s[t + 4];
      if (lane < 34)
        dma16(Htab2 + (size_t)tk * RS + lane * 4, &slots[sd][0]);
    }
    // vp partial over own 32 columns (packed), 4 chains of depth 4
    f32x2 a0{0.f,0.f}, a1{0.f,0.f}, a2{0.f,0.f}, a3{0.f,0.f};
#pragma unroll
    for (int m = 0; m < 4; ++m) {
      pkfma(a0, kc[4 * m + 0], M2[4 * m + 0]);
      pkfma(a1, kc[4 * m + 1], M2[4 * m + 1]);
      pkfma(a2, kc[4 * m + 2], M2[4 * m + 2]);
      pkfma(a3, kc[4 * m + 3], M2[4 * m + 3]);
    }
    float vp = ((a0.x + a0.y) + (a1.x + a1.y)) + ((a2.x + a2.y) + (a3.x + a3.y));
    vp = dppadd<0xB1>(vp);                 // quad xor1
    vp = dppadd<0x4E>(vp);                 // quad xor2 -> full row dot in all 4 lanes
    float e = fmaf(-vp, inv_c, ki_c);
    // ||e||^2: e is quad-replicated; 4-level tree counts each row exactly once
    float s = e * e;
    s = dppadd<0x141>(s);
    s = dppadd<0x140>(s);
    s = dppadd<0x142>(s);
    s = dppadd<0x143>(s);
    if (lane == 63) red_s[p][wv] = s;
    barrier_lgkm();                        // lgkmcnt(0)+s_barrier, NO vmcnt drain

    float4 ra = *(const float4*)&red_s[p][0];  // issue early: overlaps refill
    float4 rb = *(const float4*)&red_s[p][4];
    wait_vmN(nwait);
    {                                      // refill k_{t+1} -> kn (consumed next step)
      const float4* kp = (const float4*)&slots[sn][kbase];
#pragma unroll
      for (int m = 0; m < 8; ++m) {
        float4 tq = kp[m];
        kn[2 * m]     = f32x2{tq.x, tq.y};
        kn[2 * m + 1] = f32x2{tq.z, tq.w};
      }
      ki_n = slots[sn][iofs];
      float2 kv = *(const float2*)&slots[sn][132];
      kk_n = kv.x; inv_n = kv.y;
    }
    float ne2 = ((ra.x + ra.y) + (ra.z + ra.w)) + ((rb.x + rb.y) + (rb.z + rb.w));
    float ge = (ne2 > 0.16f * kk_c) ? e : 0.0f;   // ||e|| > 0.4*||v||
    f32x2 ev{ge, ge};
#pragma unroll
    for (int m = 0; m < 16; ++m) pkfma(M2[m], ev, kc[m]);
    // pin kn AFTER the update so its loads hide under red-read + update
#pragma unroll
    for (int m = 0; m < 16; ++m) asm volatile("" : "+v"(kn[m]));
    asm volatile("" : "+v"(ki_n), "+v"(kk_n), "+v"(inv_n));
  };

  // steps 0..2039 (2040 = 8*255). Slot t&7 holds k_t; DMA fills (t+4)&7.
  for (int t = 0; t < 2040; t += 8) {
    step(kA, kiA, kkA, invA, kB, kiB, kkB, invB, t + 0, 0, 1, 4, 3);
    step(kB, kiB, kkB, invB, kA, kiA, kkA, invA, t + 1, 1, 2, 5, 3);
    step(kA, kiA, kkA, invA, kB, kiB, kkB, invB, t + 2, 2, 3, 6, 3);
    step(kB, kiB, kkB, invB, kA, kiA, kkA, invA, t + 3, 3, 4, 7, 3);
    step(kA, kiA, kkA, invA, kB, kiB, kkB, invB, t + 4, 0, 5, 0, 3);
    step(kB, kiB, kkB, invB, kA, kiA, kkA, invA, t + 5, 1, 6, 1, 3);
    step(kA, kiA, kkA, invA, kB, kiB, kkB, invB, t + 6, 2, 7, 2, 3);
    step(kB, kiB, kkB, invB, kA, kiA, kkA, invA, t + 7, 3, 0, 3, 3);
  }
  // tail: steps 2040..2046; last DMA at t=2043 (k_2047); drain vmcnt 3 -> 0
  step(kA, kiA, kkA, invA, kB, kiB, kkB, invB, 2040, 0, 1, 4, 3);
  step(kB, kiB, kkB, invB, kA, kiA, kkA, invA, 2041, 1, 2, 5, 3);
  step(kA, kiA, kkA, invA, kB, kiB, kkB, invB, 2042, 2, 3, 6, 3);
  step(kB, kiB, kkB, invB, kA, kiA, kkA, invA, 2043, 3, 4, 7, 3);
  step(kA, kiA, kkA, invA, kB, kiB, kkB, invB, 2044, 0, 5, 0, 2);
  step(kB, kiB, kkB, invB, kA, kiA, kkA, invA, 2045, 1, 6, 1, 1);
  step(kA, kiA, kkA, invA, kB, kiB, kkB, invB, 2046, 2, 7, 2, 0);

  // r = M_fin @ h(seq[b, L-1])  (kB = k_2047)
  {
    f32x2 a0{0.f,0.f}, a1{0.f,0.f}, a2{0.f,0.f}, a3{0.f,0.f};
#pragma unroll
    for (int m = 0; m < 4; ++m) {
      pkfma(a0, kB[4 * m + 0], M2[4 * m + 0]);
      pkfma(a1, kB[4 * m + 1], M2[4 * m + 1]);
      pkfma(a2, kB[4 * m + 2], M2[4 * m + 2]);
      pkfma(a3, kB[4 * m + 3], M2[4 * m + 3]);
    }
    float vp = ((a0.x + a0.y) + (a1.x + a1.y)) + ((a2.x + a2.y) + (a3.x + a3.y));
    vp = dppadd<0xB1>(vp);
    vp = dppadd<0x4E>(vp);
    if (q == 0) r_s[i] = vp;
  }
  __syncthreads();

  // rr[b,:] = r @ Wrp + brp  (512 threads: 4 row-groups of 32)
  const int j = tid & 127;
  const int g = tid >> 7;
  float pac[2] = {0.f, 0.f};
#pragma unroll
  for (int m = 0; m < 32; ++m) {
    pac[m & 1] = fmaf(r_s[g * 32 + m],
                      Wrp[(size_t)(g * 32 + m) * 128 + j], pac[m & 1]);
  }
  p2_s[g][j] = pac[0] + pac[1];
  __syncthreads();
  if (tid < 128) {
    rr[(size_t)b * 128 + tid] =
        p2_s[0][tid] + p2_s[1][tid] + p2_s[2][tid] + p2_s[3][tid] + brp[tid];
  }
}

// ---------------------------------------------------------------------------
// Kernel C: out[b,v] = rr[b,:] @ Wout[:,v] + bout[v]  (unchanged)
// ---------------------------------------------------------------------------
__global__ __launch_bounds__(256, 1) void out_kernel(
    const float* __restrict__ rr,
    const float* __restrict__ Wout,
    const float* __restrict__ bout,
    float* __restrict__ out)
{
  const int tid = threadIdx.x;
  const int v = blockIdx.x * 64 + (tid & 63);
  const int bg = tid >> 6;
  const int b0 = blockIdx.y * 64;

  __shared__ float4 rs4[64][32];
  for (int idx = tid; idx < 2048; idx += 256) {
    int bb = idx >> 5, q = idx & 31;
    rs4[bb][q] = ((const float4*)rr)[(size_t)(b0 + bb) * 32 + q];
  }
  __syncthreads();

  float acc[16];
#pragma unroll
  for (int m = 0; m < 16; ++m) acc[m] = 0.0f;

  for (int h4 = 0; h4 < 32; ++h4) {
    float w0 = Wout[(size_t)(4 * h4 + 0) * VV + v];
    float w1 = Wout[(size_t)(4 * h4 + 1) * VV + v];
    float w2 = Wout[(size_t)(4 * h4 + 2) * VV + v];
    float w3 = Wout[(size_t)(4 * h4 + 3) * VV + v];
#pragma unroll
    for (int m = 0; m < 16; ++m) {
      float4 rv = rs4[bg * 16 + m][h4];
      float t = rv.x * w0;
      t = fmaf(rv.y, w1, t);
      t = fmaf(rv.z, w2, t);
      t = fmaf(rv.w, w3, t);
      acc[m] += t;
    }
  }
  float bo = bout[v];
#pragma unroll
  for (int m = 0; m < 16; ++m) {
    out[(size_t)(b0 + bg * 16 + m) * VV + v] = acc[m] + bo;
  }
}

// ---------------------------------------------------------------------------
extern "C" void kernel_launch(void* const* d_in, const int* in_sizes, int n_in,
                              void* d_out, int out_size, void* d_ws, size_t ws_size,
                              hipStream_t stream)
{
  const int* seq      = (const int*)d_in[0];
  const float* embed  = (const float*)d_in[1];
  const float* W1     = (const float*)d_in[2];
  const float* b1     = (const float*)d_in[3];
  const float* W2     = (const float*)d_in[4];
  const float* b2     = (const float*)d_in[5];
  const float* gamma  = (const float*)d_in[6];
  const float* beta   = (const float*)d_in[7];
  const float* Wrp    = (const float*)d_in[8];
  const float* brp    = (const float*)d_in[9];
  const float* Wout   = (const float*)d_in[10];
  const float* bout   = (const float*)d_in[11];
  float* out          = (float*)d_out;

  char* ws = (char*)d_ws;
  float* Htab2 = (float*)ws;                         // 32000*136*4 = 17,408,000 B
  float* rr    = (float*)(ws + 17408000);            //    131,072 B

  hipLaunchKernelGGL(build_htab_kernel, dim3(256), dim3(256), 0, stream,
                     embed, W1, b1, W2, b2, gamma, beta, Htab2);
  hipLaunchKernelGGL(scan_kernel, dim3(BB), dim3(512), 0, stream,
                     seq, Htab2, Wrp, brp, rr);
  hipLaunchKernelGGL(out_kernel, dim3(VV / 64, 4), dim3(256), 0, stream,
                     rr, Wout, bout, out);
}